// Round 1
// baseline (622.989 us; speedup 1.0000x reference)
//
#include <hip/hip_runtime.h>

#define NROWS    262144   // 16 * 16384
#define DIMS     64
#define KCODES   512
#define MTILE    64       // rows per block
#define CHUNK    256      // cols per LDS chunk
#define NCHUNK   2
#define NTHREADS 512

// ---------------------------------------------------------------------------
// prep: embedT[k][d] = embed[d][k]; enorm[k] = sum_d embed[d][k]^2 (numpy
// pairwise-8 order); zero the likelihood accumulator.
// grid <<<512, 64>>> : block = one code k, lane = d.
// ---------------------------------------------------------------------------
__global__ void prep_kernel(const float* __restrict__ embed,
                            float* __restrict__ embedT,
                            float* __restrict__ enorm,
                            float* __restrict__ lik) {
    int k = blockIdx.x;
    int d = threadIdx.x;
    float v = embed[d * KCODES + k];
    embedT[k * DIMS + d] = v;
    float sq = __fmul_rn(v, v);
    // numpy pairwise: r_j = sq_j + sq_{j+8} + ... (sequential), j = d & 7
    int j = d & 7;
    float r = __shfl(sq, j, 64);
#pragma unroll
    for (int i = 1; i < 8; ++i)
        r = __fadd_rn(r, __shfl(sq, j + 8 * i, 64));
    // combine ((r0+r1)+(r2+r3)) + ((r4+r5)+(r6+r7)) via xor tree (bitwise exact)
    float t;
    t = __shfl_xor(r, 1, 64); r = __fadd_rn(r, t);
    t = __shfl_xor(r, 2, 64); r = __fadd_rn(r, t);
    t = __shfl_xor(r, 4, 64); r = __fadd_rn(r, t);
    if (d == 0) { enorm[k] = r; lik[k] = 0.0f; }
}

// ---------------------------------------------------------------------------
// main: fused GEMM (dot of each row with all 512 codes) + softmax + argmax +
// hard-gather write + likelihood partial accumulation.
// grid <<<4096, 512>>>. Block: 64 rows x 512 cols.
// Thread (cg = tid&63, rg = tid>>6): 8 rows (rg*8..) x 4 cols (cg*4..) per
// 256-col chunk -> acc[2][8][4]. Wave = one rg = 8 full rows (in-wave softmax).
// LDS: one 64KB embed chunk [64 d][256 c]; aliased as lik scratch post-GEMM.
// ---------------------------------------------------------------------------
__launch_bounds__(NTHREADS, 4)
__global__ void main_kernel(const float* __restrict__ x,
                            const float* __restrict__ embed,
                            const float* __restrict__ sigma,
                            const float* __restrict__ embedT,
                            const float* __restrict__ enorm,
                            float* __restrict__ lik,
                            float* __restrict__ out) {
    __shared__ float e_lds[DIMS * CHUNK];   // 64 KB exactly

    const int tid = threadIdx.x;
    const int cg  = tid & 63;        // col group (4 cols)
    const int rg  = tid >> 6;        // row group (8 rows), == wave id
    const int rowbase = blockIdx.x * MTILE + rg * 8;

    const float sigma_v = sigma[0];

    float acc[NCHUNK][8][4];
#pragma unroll
    for (int c = 0; c < NCHUNK; ++c)
#pragma unroll
        for (int r = 0; r < 8; ++r)
#pragma unroll
            for (int q = 0; q < 4; ++q) acc[c][r][q] = 0.0f;

    const float4* __restrict__ x4  = reinterpret_cast<const float4*>(x);
    const float4* __restrict__ eg4 = reinterpret_cast<const float4*>(embed);

#pragma unroll
    for (int ch = 0; ch < NCHUNK; ++ch) {
        __syncthreads();   // protect previous chunk's readers
        // stage embed chunk: wave-contiguous rows (one d-row per wave-iter)
#pragma unroll
        for (int i = 0; i < 8; ++i) {
            int f4 = tid + i * NTHREADS;          // 0..4095
            int d  = f4 >> 6;
            int c4 = f4 & 63;
            reinterpret_cast<float4*>(e_lds)[d * 64 + c4] =
                eg4[d * 128 + ch * 64 + c4];
        }
        __syncthreads();

        const float4* e4 = reinterpret_cast<const float4*>(e_lds);
#pragma unroll 2
        for (int d = 0; d < DIMS; d += 4) {
            float4 e0 = e4[(d + 0) * 64 + cg];
            float4 e1 = e4[(d + 1) * 64 + cg];
            float4 e2 = e4[(d + 2) * 64 + cg];
            float4 e3 = e4[(d + 3) * 64 + cg];
            int d4 = d >> 2;
#pragma unroll
            for (int r = 0; r < 8; ++r) {
                float4 xv = x4[(rowbase + r) * 16 + d4];
                // ascending-d sequential fma chain per (r,col)
                acc[ch][r][0] = fmaf(xv.x, e0.x, acc[ch][r][0]);
                acc[ch][r][1] = fmaf(xv.x, e0.y, acc[ch][r][1]);
                acc[ch][r][2] = fmaf(xv.x, e0.z, acc[ch][r][2]);
                acc[ch][r][3] = fmaf(xv.x, e0.w, acc[ch][r][3]);
                acc[ch][r][0] = fmaf(xv.y, e1.x, acc[ch][r][0]);
                acc[ch][r][1] = fmaf(xv.y, e1.y, acc[ch][r][1]);
                acc[ch][r][2] = fmaf(xv.y, e1.z, acc[ch][r][2]);
                acc[ch][r][3] = fmaf(xv.y, e1.w, acc[ch][r][3]);
                acc[ch][r][0] = fmaf(xv.z, e2.x, acc[ch][r][0]);
                acc[ch][r][1] = fmaf(xv.z, e2.y, acc[ch][r][1]);
                acc[ch][r][2] = fmaf(xv.z, e2.z, acc[ch][r][2]);
                acc[ch][r][3] = fmaf(xv.z, e2.w, acc[ch][r][3]);
                acc[ch][r][0] = fmaf(xv.w, e3.x, acc[ch][r][0]);
                acc[ch][r][1] = fmaf(xv.w, e3.y, acc[ch][r][1]);
                acc[ch][r][2] = fmaf(xv.w, e3.z, acc[ch][r][2]);
                acc[ch][r][3] = fmaf(xv.w, e3.w, acc[ch][r][3]);
            }
        }
    }

    // ---- xnorm for the wave's 8 rows, numpy pairwise-8 order ----
    // lane cg = r_l*8 + j_l computes partial r_{j_l} of row r_l
    const int r_l = cg >> 3;
    const int j_l = cg & 7;
    float xr;
    {
        const float* xp = x + (size_t)(rowbase - rg * 8 + rg * 8 + r_l) * DIMS + j_l;
        // rowbase already includes rg*8; row for xnorm = rowbase + r_l
        xp = x + (size_t)(rowbase + r_l) * DIMS + j_l;
        float v0 = xp[0];
        float s = __fmul_rn(v0, v0);
#pragma unroll
        for (int i = 1; i < 8; ++i) {
            float v = xp[8 * i];
            s = __fadd_rn(s, __fmul_rn(v, v));
        }
        xr = s;
    }
    {
        float t;
        t = __shfl_xor(xr, 1, 64); xr = __fadd_rn(xr, t);
        t = __shfl_xor(xr, 2, 64); xr = __fadd_rn(xr, t);
        t = __shfl_xor(xr, 4, 64); xr = __fadd_rn(xr, t);
    }
    // lane r*8+j now holds xnorm of row r

    // enorm for this thread's 8 cols
    float en[NCHUNK][4];
#pragma unroll
    for (int c = 0; c < NCHUNK; ++c)
#pragma unroll
        for (int q = 0; q < 4; ++q)
            en[c][q] = enorm[c * CHUNK + cg * 4 + q];

    float likpart[NCHUNK][4];
#pragma unroll
    for (int c = 0; c < NCHUNK; ++c)
#pragma unroll
        for (int q = 0; q < 4; ++q) likpart[c][q] = 0.0f;

#pragma unroll
    for (int r = 0; r < 8; ++r) {
        float xn = __shfl(xr, r * 8, 64);
        // z = -sigma * ((xnorm - 2*dot) + enorm), np-assembly order
        float z[NCHUNK][4];
        float m = -INFINITY;
#pragma unroll
        for (int c = 0; c < NCHUNK; ++c)
#pragma unroll
            for (int q = 0; q < 4; ++q) {
                float dot  = acc[c][r][q];
                float td   = __fsub_rn(xn, __fmul_rn(2.0f, dot));
                float dist = __fadd_rn(td, en[c][q]);
                float zz   = __fmul_rn(-sigma_v, dist);
                z[c][q] = zz;
                m = fmaxf(m, zz);
            }
#pragma unroll
        for (int mask = 1; mask < 64; mask <<= 1)
            m = fmaxf(m, __shfl_xor(m, mask, 64));

        float ev[NCHUNK][4];
        float s = 0.0f;
        float bv = -1.0f;
        int   bc = KCODES;
#pragma unroll
        for (int c = 0; c < NCHUNK; ++c)
#pragma unroll
            for (int q = 0; q < 4; ++q) {
                float ee = expf(__fsub_rn(z[c][q], m));
                ev[c][q] = ee;
                s += ee;
                int col = c * CHUNK + cg * 4 + q;
                if (ee > bv) { bv = ee; bc = col; }   // first-index tiebreak
            }
#pragma unroll
        for (int mask = 1; mask < 64; mask <<= 1)
            s += __shfl_xor(s, mask, 64);
#pragma unroll
        for (int mask = 1; mask < 64; mask <<= 1) {
            float ov = __shfl_xor(bv, mask, 64);
            int   oc = __shfl_xor(bc, mask, 64);
            if (ov > bv || (ov == bv && oc < bc)) { bv = ov; bc = oc; }
        }

        float invS = 1.0f / s;
#pragma unroll
        for (int c = 0; c < NCHUNK; ++c)
#pragma unroll
            for (int q = 0; q < 4; ++q)
                likpart[c][q] = fmaf(ev[c][q], invS, likpart[c][q]);

        // hard-gather write: quantize[row][cg] = embedT[bc][cg]
        int row = rowbase + r;
        out[(size_t)row * DIMS + cg] = embedT[bc * DIMS + cg];
    }

    // ---- block-level likelihood reduction (reuse e_lds) ----
    float* red = e_lds;
    __syncthreads();
    red[tid] = 0.0f;
    __syncthreads();
#pragma unroll
    for (int c = 0; c < NCHUNK; ++c)
#pragma unroll
        for (int q = 0; q < 4; ++q)
            atomicAdd(&red[c * CHUNK + cg * 4 + q], likpart[c][q]);
    __syncthreads();
    atomicAdd(&lik[tid], red[tid]);
}

// ---------------------------------------------------------------------------
// finish: likelihoods = lik_sum / N; quant_loss = 0.25 * mean(p*(log p - log(l+eps)))
// ---------------------------------------------------------------------------
__global__ void finish_kernel(const float* __restrict__ lik,
                              float* __restrict__ out) {
    int tid = threadIdx.x;   // 512 threads
    float l = lik[tid] / 262144.0f;     // exact: divide by 2^18
    out[16777217 + tid] = l;
    const float p = 1.0f / 512.0f;
    float term = __fmul_rn(p, __fsub_rn(logf(p), logf(l + 1e-10f)));
#pragma unroll
    for (int mask = 1; mask < 64; mask <<= 1)
        term += __shfl_xor(term, mask, 64);
    __shared__ float ws[8];
    if ((tid & 63) == 0) ws[tid >> 6] = term;
    __syncthreads();
    if (tid == 0) {
        float ssum = 0.0f;
        for (int i = 0; i < 8; ++i) ssum += ws[i];
        out[16777216] = 0.25f * (ssum / 512.0f);
    }
}

extern "C" void kernel_launch(void* const* d_in, const int* in_sizes, int n_in,
                              void* d_out, int out_size, void* d_ws, size_t ws_size,
                              hipStream_t stream) {
    const float* x     = (const float*)d_in[0];
    const float* embed = (const float*)d_in[1];
    const float* sigma = (const float*)d_in[2];
    float* out = (float*)d_out;
    float* ws  = (float*)d_ws;

    float* embedT = ws;             // 512*64 = 32768 floats
    float* enorm  = ws + 32768;     // 512 floats
    float* lik    = ws + 33280;     // 512 floats

    prep_kernel<<<KCODES, DIMS, 0, stream>>>(embed, embedT, enorm, lik);
    main_kernel<<<NROWS / MTILE, NTHREADS, 0, stream>>>(x, embed, sigma,
                                                        embedT, enorm, lik, out);
    finish_kernel<<<1, NTHREADS, 0, stream>>>(lik, out);
}

// Round 2
// 614.915 us; speedup vs baseline: 1.0131x; 1.0131x over previous
//
#include <hip/hip_runtime.h>

#define NROWS    262144   // 16 * 16384
#define DIMS     64
#define KCODES   512
#define MTILE    64       // rows per block
#define CHUNK    256      // cols per LDS chunk
#define NCHUNK   2
#define NTHREADS 512

// ---------------------------------------------------------------------------
// prep: embedT[k][d] = embed[d][k]; enorm[k] = sum_d embed[d][k]^2 (numpy
// pairwise-8 order); zero the likelihood accumulator.
// grid <<<512, 64>>> : block = one code k, lane = d.
// ---------------------------------------------------------------------------
__global__ void prep_kernel(const float* __restrict__ embed,
                            float* __restrict__ embedT,
                            float* __restrict__ enorm,
                            float* __restrict__ lik) {
    int k = blockIdx.x;
    int d = threadIdx.x;
    float v = embed[d * KCODES + k];
    embedT[k * DIMS + d] = v;
    float sq = __fmul_rn(v, v);
    // numpy pairwise: r_j = sq_j + sq_{j+8} + ... (sequential), j = d & 7
    int j = d & 7;
    float r = __shfl(sq, j, 64);
#pragma unroll
    for (int i = 1; i < 8; ++i)
        r = __fadd_rn(r, __shfl(sq, j + 8 * i, 64));
    // combine ((r0+r1)+(r2+r3)) + ((r4+r5)+(r6+r7)) via xor tree (bitwise exact)
    float t;
    t = __shfl_xor(r, 1, 64); r = __fadd_rn(r, t);
    t = __shfl_xor(r, 2, 64); r = __fadd_rn(r, t);
    t = __shfl_xor(r, 4, 64); r = __fadd_rn(r, t);
    if (d == 0) { enorm[k] = r; lik[k] = 0.0f; }
}

// ---------------------------------------------------------------------------
// main: fused GEMM (dot of each row with all 512 codes) + softmax + argmax +
// hard-gather write + likelihood partial accumulation.
// grid <<<4096, 512>>>. Block: 64 rows x 512 cols.
// Thread (cg = tid&63, rg = tid>>6): 8 rows (rg*8..) x 4 cols (cg*4..) per
// 256-col chunk -> acc[2][8][4]. Wave = one rg = 8 full rows (in-wave softmax).
// LDS: one 64KB embed chunk [64 d][256 c]; aliased as lik scratch post-GEMM.
// Epilogue is IN-PLACE over acc (z then ev overwrite acc) to keep peak live
// VGPRs under the 128 cap — round 1's separate z/ev arrays spilled to scratch
// (352 MB WRITE_SIZE vs 67 MB expected).
// ---------------------------------------------------------------------------
__launch_bounds__(NTHREADS, 4)
__global__ void main_kernel(const float* __restrict__ x,
                            const float* __restrict__ embed,
                            const float* __restrict__ sigma,
                            const float* __restrict__ embedT,
                            const float* __restrict__ enorm,
                            float* __restrict__ lik,
                            float* __restrict__ out) {
    __shared__ float e_lds[DIMS * CHUNK];   // 64 KB exactly

    const int tid = threadIdx.x;
    const int cg  = tid & 63;        // col group (4 cols)
    const int rg  = tid >> 6;        // row group (8 rows), == wave id
    const int rowbase = blockIdx.x * MTILE + rg * 8;

    const float sigma_v = sigma[0];

    float acc[NCHUNK][8][4];
#pragma unroll
    for (int c = 0; c < NCHUNK; ++c)
#pragma unroll
        for (int r = 0; r < 8; ++r)
#pragma unroll
            for (int q = 0; q < 4; ++q) acc[c][r][q] = 0.0f;

    const float4* __restrict__ x4  = reinterpret_cast<const float4*>(x);
    const float4* __restrict__ eg4 = reinterpret_cast<const float4*>(embed);

#pragma unroll
    for (int ch = 0; ch < NCHUNK; ++ch) {
        __syncthreads();   // protect previous chunk's readers
        // stage embed chunk: wave-contiguous rows (one d-row per wave-iter)
#pragma unroll
        for (int i = 0; i < 8; ++i) {
            int f4 = tid + i * NTHREADS;          // 0..4095
            int d  = f4 >> 6;
            int c4 = f4 & 63;
            reinterpret_cast<float4*>(e_lds)[d * 64 + c4] =
                eg4[d * 128 + ch * 64 + c4];
        }
        __syncthreads();

        const float4* e4 = reinterpret_cast<const float4*>(e_lds);
#pragma unroll 2
        for (int d = 0; d < DIMS; d += 4) {
            float4 e0 = e4[(d + 0) * 64 + cg];
            float4 e1 = e4[(d + 1) * 64 + cg];
            float4 e2 = e4[(d + 2) * 64 + cg];
            float4 e3 = e4[(d + 3) * 64 + cg];
            int d4 = d >> 2;
#pragma unroll
            for (int r = 0; r < 8; ++r) {
                float4 xv = x4[(rowbase + r) * 16 + d4];
                // ascending-d sequential fma chain per (r,col)
                acc[ch][r][0] = fmaf(xv.x, e0.x, acc[ch][r][0]);
                acc[ch][r][1] = fmaf(xv.x, e0.y, acc[ch][r][1]);
                acc[ch][r][2] = fmaf(xv.x, e0.z, acc[ch][r][2]);
                acc[ch][r][3] = fmaf(xv.x, e0.w, acc[ch][r][3]);
                acc[ch][r][0] = fmaf(xv.y, e1.x, acc[ch][r][0]);
                acc[ch][r][1] = fmaf(xv.y, e1.y, acc[ch][r][1]);
                acc[ch][r][2] = fmaf(xv.y, e1.z, acc[ch][r][2]);
                acc[ch][r][3] = fmaf(xv.y, e1.w, acc[ch][r][3]);
                acc[ch][r][0] = fmaf(xv.z, e2.x, acc[ch][r][0]);
                acc[ch][r][1] = fmaf(xv.z, e2.y, acc[ch][r][1]);
                acc[ch][r][2] = fmaf(xv.z, e2.z, acc[ch][r][2]);
                acc[ch][r][3] = fmaf(xv.z, e2.w, acc[ch][r][3]);
                acc[ch][r][0] = fmaf(xv.w, e3.x, acc[ch][r][0]);
                acc[ch][r][1] = fmaf(xv.w, e3.y, acc[ch][r][1]);
                acc[ch][r][2] = fmaf(xv.w, e3.z, acc[ch][r][2]);
                acc[ch][r][3] = fmaf(xv.w, e3.w, acc[ch][r][3]);
            }
        }
    }

    // ---- xnorm for the wave's 8 rows, numpy pairwise-8 order ----
    // lane cg = r_l*8 + j_l computes partial r_{j_l} of row r_l
    const int r_l = cg >> 3;
    const int j_l = cg & 7;
    float xr;
    {
        const float* xp = x + (size_t)(rowbase + r_l) * DIMS + j_l;
        float v0 = xp[0];
        float s = __fmul_rn(v0, v0);
#pragma unroll
        for (int i = 1; i < 8; ++i) {
            float v = xp[8 * i];
            s = __fadd_rn(s, __fmul_rn(v, v));
        }
        xr = s;
    }
    {
        float t;
        t = __shfl_xor(xr, 1, 64); xr = __fadd_rn(xr, t);
        t = __shfl_xor(xr, 2, 64); xr = __fadd_rn(xr, t);
        t = __shfl_xor(xr, 4, 64); xr = __fadd_rn(xr, t);
    }
    // lane r*8+j now holds xnorm of row r

    // enorm for this thread's 8 cols
    float en[NCHUNK][4];
#pragma unroll
    for (int c = 0; c < NCHUNK; ++c)
#pragma unroll
        for (int q = 0; q < 4; ++q)
            en[c][q] = enorm[c * CHUNK + cg * 4 + q];

    float likpart[NCHUNK][4];
#pragma unroll
    for (int c = 0; c < NCHUNK; ++c)
#pragma unroll
        for (int q = 0; q < 4; ++q) likpart[c][q] = 0.0f;

#pragma unroll
    for (int r = 0; r < 8; ++r) {
        float xn = __shfl(xr, r * 8, 64);
        // z = -sigma * ((xnorm - 2*dot) + enorm), np-assembly order.
        // IN-PLACE: z overwrites acc[c][r][q] (dot is dead afterwards).
        float m = -INFINITY;
#pragma unroll
        for (int c = 0; c < NCHUNK; ++c)
#pragma unroll
            for (int q = 0; q < 4; ++q) {
                float dot  = acc[c][r][q];
                float td   = __fsub_rn(xn, __fmul_rn(2.0f, dot));
                float dist = __fadd_rn(td, en[c][q]);
                float zz   = __fmul_rn(-sigma_v, dist);
                acc[c][r][q] = zz;
                m = fmaxf(m, zz);
            }
#pragma unroll
        for (int mask = 1; mask < 64; mask <<= 1)
            m = fmaxf(m, __shfl_xor(m, mask, 64));

        // ev overwrites z in place
        float s = 0.0f;
        float bv = -1.0f;
        int   bc = KCODES;
#pragma unroll
        for (int c = 0; c < NCHUNK; ++c)
#pragma unroll
            for (int q = 0; q < 4; ++q) {
                float ee = expf(__fsub_rn(acc[c][r][q], m));
                acc[c][r][q] = ee;
                s += ee;
                int col = c * CHUNK + cg * 4 + q;
                if (ee > bv) { bv = ee; bc = col; }   // first-index tiebreak
            }
#pragma unroll
        for (int mask = 1; mask < 64; mask <<= 1)
            s += __shfl_xor(s, mask, 64);
#pragma unroll
        for (int mask = 1; mask < 64; mask <<= 1) {
            float ov = __shfl_xor(bv, mask, 64);
            int   oc = __shfl_xor(bc, mask, 64);
            if (ov > bv || (ov == bv && oc < bc)) { bv = ov; bc = oc; }
        }

        float invS = 1.0f / s;
#pragma unroll
        for (int c = 0; c < NCHUNK; ++c)
#pragma unroll
            for (int q = 0; q < 4; ++q)
                likpart[c][q] = fmaf(acc[c][r][q], invS, likpart[c][q]);

        // hard-gather write: quantize[row][cg] = embedT[bc][cg]
        // nontemporal: avoid write-allocate RFO on the 64 MB output
        int row = rowbase + r;
        __builtin_nontemporal_store(embedT[bc * DIMS + cg],
                                    &out[(size_t)row * DIMS + cg]);
    }

    // ---- block-level likelihood reduction (reuse e_lds) ----
    float* red = e_lds;
    __syncthreads();
    red[tid] = 0.0f;
    __syncthreads();
#pragma unroll
    for (int c = 0; c < NCHUNK; ++c)
#pragma unroll
        for (int q = 0; q < 4; ++q)
            atomicAdd(&red[c * CHUNK + cg * 4 + q], likpart[c][q]);
    __syncthreads();
    atomicAdd(&lik[tid], red[tid]);
}

// ---------------------------------------------------------------------------
// finish: likelihoods = lik_sum / N; quant_loss = 0.25 * mean(p*(log p - log(l+eps)))
// ---------------------------------------------------------------------------
__global__ void finish_kernel(const float* __restrict__ lik,
                              float* __restrict__ out) {
    int tid = threadIdx.x;   // 512 threads
    float l = lik[tid] / 262144.0f;     // exact: divide by 2^18
    out[16777217 + tid] = l;
    const float p = 1.0f / 512.0f;
    float term = __fmul_rn(p, __fsub_rn(logf(p), logf(l + 1e-10f)));
#pragma unroll
    for (int mask = 1; mask < 64; mask <<= 1)
        term += __shfl_xor(term, mask, 64);
    __shared__ float ws[8];
    if ((tid & 63) == 0) ws[tid >> 6] = term;
    __syncthreads();
    if (tid == 0) {
        float ssum = 0.0f;
        for (int i = 0; i < 8; ++i) ssum += ws[i];
        out[16777216] = 0.25f * (ssum / 512.0f);
    }
}

extern "C" void kernel_launch(void* const* d_in, const int* in_sizes, int n_in,
                              void* d_out, int out_size, void* d_ws, size_t ws_size,
                              hipStream_t stream) {
    const float* x     = (const float*)d_in[0];
    const float* embed = (const float*)d_in[1];
    const float* sigma = (const float*)d_in[2];
    float* out = (float*)d_out;
    float* ws  = (float*)d_ws;

    float* embedT = ws;             // 512*64 = 32768 floats
    float* enorm  = ws + 32768;     // 512 floats
    float* lik    = ws + 33280;     // 512 floats

    prep_kernel<<<KCODES, DIMS, 0, stream>>>(embed, embedT, enorm, lik);
    main_kernel<<<NROWS / MTILE, NTHREADS, 0, stream>>>(x, embed, sigma,
                                                        embedT, enorm, lik, out);
    finish_kernel<<<1, NTHREADS, 0, stream>>>(lik, out);
}